// Round 5
// baseline (229.408 us; speedup 1.0000x reference)
//
#include <hip/hip_runtime.h>
#include <hip/hip_fp16.h>

// b=2, c=64, 48x48 -> n=2304, heads=4, hd=16. n = 9*256 = 144*16.
// r22: cache-free fused attention, 8-ROW TILES (r21 post-mortem: fusion
// killed HBM traffic (44MB->1.5MB) but 78KB LDS -> 2 blocks/CU (35% occ),
// 2 rows/wave serial chain, and a broken swizzle (4-way PV conflicts) ->
// 86us. Now: 43.3KB LDS -> 3 blocks/CU, grid 2304 = exactly 3 clean
// rounds, 1 row/wave top-k, legacy 2320-half row stride (4640B = 32B mod
// 128 -> rows bank-staggered, PV reads <=2-way=free). Phase 1 recomputes
// QK^T with 8 unique A-rows duplicated (quads 2-3 discard; MFMA is 3%
// util, 2x MFMA is free; k2 re-reads are L2-resident). Output bit-path
// preserved: phase-2 body verbatim from r21 (absmax-stable lineage),
// phase-3 = legacy 4x576 j-split per 4-row group, same reduce order.
// SEPARATE k_proj (r17: fused atomicAdd 60->94us - do not revisit).

typedef _Float16 half8_t __attribute__((ext_vector_type(8)));
typedef float floatx4 __attribute__((ext_vector_type(4)));

union HU { unsigned short s; _Float16 h; };
__device__ __forceinline__ _Float16 ubits_h(unsigned short u) {
  HU c; c.s = u; return c.h;
}
// ascending 16-bit key -> the f16 value it encodes
__device__ __forceinline__ _Float16 key_h(unsigned k) {
  unsigned short u = (k & 0x8000u) ? (unsigned short)(k & 0x7FFFu)
                                   : (unsigned short)((~k) & 0xFFFFu);
  return ubits_h(u);
}

// Wave-wide select over a 256-bucket histogram packed as 128 u32 (2 u16
// counters per word): returns (bucket, count-strictly-above-bucket) for
// the keepN-th largest, scanning from the TOP. Lane l owns buckets
// 4l..4l+3 (words 2l, 2l+1).
__device__ __forceinline__ uint2 hist_select_p(const unsigned* h, int lane,
                                               unsigned keepN) {
  uint2 w = ((const uint2*)h)[lane];
  unsigned c0 = w.x & 0xFFFFu, c1 = w.x >> 16;
  unsigned c2 = w.y & 0xFFFFu, c3 = w.y >> 16;
  unsigned inc = c0 + c1 + c2 + c3;
#pragma unroll
  for (int off = 1; off < 64; off <<= 1) {
    unsigned t = __shfl_up(inc, off);
    if (lane >= off) inc += t;
  }
  unsigned total = __shfl(inc, 63);
  unsigned above = total - inc;  // strictly above this lane's 4 buckets
  unsigned a3 = above;
  unsigned a2 = a3 + c3;
  unsigned a1 = a2 + c2;
  unsigned a0 = a1 + c1;
  bool has = false;
  unsigned B_l = 0, A_l = 0;
  if (a3 < keepN && a3 + c3 >= keepN) { has = true; B_l = lane * 4 + 3; A_l = a3; }
  else if (a2 < keepN && a2 + c2 >= keepN) { has = true; B_l = lane * 4 + 2; A_l = a2; }
  else if (a1 < keepN && a1 + c1 >= keepN) { has = true; B_l = lane * 4 + 1; A_l = a1; }
  else if (a0 < keepN && a0 + c0 >= keepN) { has = true; B_l = lane * 4 + 0; A_l = a0; }
  unsigned long long m = __ballot(has);
  int src = __ffsll(m) - 1;
  return make_uint2(__shfl(B_l, src), __shfl(A_l, src));
}

// K1: 1x1 conv, 4 output channels per block. grid = 2*48*9 = 864;
// also zeroes ent[] (replaces memset dispatch).
__global__ __launch_bounds__(256) void k_qkv(const float* __restrict__ x,
                                             const float* __restrict__ W,
                                             const float* __restrict__ bias,
                                             float* __restrict__ out,
                                             float* __restrict__ ent) {
  if (blockIdx.x == 0 && threadIdx.x < 8) ent[threadIdx.x] = 0.f;
  int blk = blockIdx.x;
  int chunk = blk % 9;
  int og = (blk / 9) % 48;
  int b = blk / (9 * 48);
  int o0 = og * 4;
  int pos = chunk * 256 + threadIdx.x;
  const float* xb = x + b * 64 * 2304 + pos;
  const float* w0 = W + (o0 + 0) * 64;
  const float* w1 = W + (o0 + 1) * 64;
  const float* w2 = W + (o0 + 2) * 64;
  const float* w3 = W + (o0 + 3) * 64;
  float a0 = bias[o0 + 0], a1 = bias[o0 + 1];
  float a2 = bias[o0 + 2], a3 = bias[o0 + 3];
#pragma unroll
  for (int c = 0; c < 64; c++) {
    float xv = xb[c * 2304];
    a0 = fmaf(w0[c], xv, a0);
    a1 = fmaf(w1[c], xv, a1);
    a2 = fmaf(w2[c], xv, a2);
    a3 = fmaf(w3[c], xv, a3);
  }
  out[(b * 192 + o0 + 0) * 2304 + pos] = a0;
  out[(b * 192 + o0 + 1) * 2304 + pos] = a1;
  out[(b * 192 + o0 + 2) * 2304 + pos] = a2;
  out[(b * 192 + o0 + 3) * 2304 + pos] = a3;
}

// K2: 3x3 depthwise conv, 8 channels per block with LDS staging; q/k
// packed per-row-half stores (2x 16B contiguous). grid = 432.
__global__ __launch_bounds__(256) void k_dw(const float* __restrict__ qkv,
                                            const float* __restrict__ Wpos,
                                            const float* __restrict__ bpos,
                                            _Float16* __restrict__ q2,
                                            _Float16* __restrict__ k2,
                                            _Float16* __restrict__ vt) {
  __shared__ float smem[8][384];  // 8 ch x 8 rows x 48 = 12.3 KB
  int blk = blockIdx.x;
  int chunk = blk % 9;
  int half = (blk / 9) % 2;
  int sel = (blk / 18) % 3;
  int head = (blk / 54) % 4;
  int b = blk / 216;
  int chbase = sel * 64 + head * 16 + half * 8;
  int bh = b * 4 + head;
  int tid = threadIdx.x;
  int p0 = chunk * 256;
  int baserow = p0 / 48;
  int rA = min(max(baserow - 1, 0), 40);  // 8-row window within [0,47]

  const float* src = qkv + (size_t)(b * 192 + chbase) * 2304;
#pragma unroll
  for (int l = 0; l < 12; l++) {
    int idx = tid + l * 256;
    int ch = idx / 384;
    int off = idx - ch * 384;
    int rr = off / 48;
    int cc = off - rr * 48;
    smem[ch][off] = src[(size_t)ch * 2304 + (rA + rr) * 48 + cc];
  }
  __syncthreads();

  int pos = p0 + tid;
  int yy = pos / 48, xx = pos - yy * 48;
  int ry = yy - rA;
  float accv[8];
#pragma unroll
  for (int d = 0; d < 8; d++) {
    const float* w = Wpos + (chbase + d) * 9;
    float a = bpos[chbase + d];
#pragma unroll
    for (int dy = -1; dy <= 1; dy++) {
      int y2 = yy + dy;
      if ((unsigned)y2 < 48u) {
#pragma unroll
        for (int dx = -1; dx <= 1; dx++) {
          int x2 = xx + dx;
          if ((unsigned)x2 < 48u)
            a = fmaf(w[(dy + 1) * 3 + (dx + 1)], smem[d][(ry + dy) * 48 + x2],
                     a);
        }
      }
    }
    accv[d] = a;
  }

  if (sel == 2) {
#pragma unroll
    for (int d = 0; d < 8; d++)
      vt[((size_t)bh * 16 + half * 8 + d) * 2304 + pos] = (_Float16)accv[d];
  } else {
    _Float16 h1[8], h2[8];
#pragma unroll
    for (int d = 0; d < 8; d++) {
      float a = (sel == 0) ? accv[d] * 0.25f : accv[d];
      h1[d] = (_Float16)a;
      h2[d] = (_Float16)(a - (float)h1[d]);
    }
    _Float16* dst = ((sel == 0) ? q2 : k2) + ((size_t)bh * 2304 + pos) * 32;
    *(uint4*)(dst + half * 8) = *(uint4*)&h1[0];
    *(uint4*)(dst + 16 + half * 8) = *(uint4*)&h2[0];
  }
}

// K3: SINGLE-PASS MFMA QK^T: entropy sums (shift-invariant, no max).
// STORE=false: no logit store, no barriers. grid = 8*144, 256 thr.
template <bool STORE>
__global__ __launch_bounds__(256) void k_ent_t(const _Float16* __restrict__ q2,
                                               const _Float16* __restrict__ k2,
                                               float* __restrict__ ent,
                                               _Float16* __restrict__ lgH) {
  __shared__ __align__(16) _Float16 tBuf[4][16][72];
  __shared__ float sWv[4][16], uWv[4][16];

  int blk = blockIdx.x;
  int rowtile = blk % 144;
  int bh = blk / 144;
  int row0 = rowtile * 16;
  int tid = threadIdx.x, lane = tid & 63, wave = tid >> 6;
  int m16 = lane & 15, quad = lane >> 4;

  const half8_t* q2v =
      (const half8_t*)(q2 + ((size_t)bh * 2304 + row0 + m16) * 32);
  half8_t A1 = q2v[quad];
  half8_t zh = {};
  half8_t A2 = (lane < 32) ? A1 : zh;
  const half8_t* kbase = (const half8_t*)(k2 + (size_t)bh * 2304 * 32);

  // s0 = sum e^a, u0 = sum a e^a  (entropy = log s0 - u0/s0; shift-inv.)
  float s[4] = {0.f, 0.f, 0.f, 0.f}, u[4] = {0.f, 0.f, 0.f, 0.f};
  for (int g = 0; g < 9; g++) {
#pragma unroll
    for (int tt = 0; tt < 4; tt++) {
      int t = g * 4 + tt;
      int col = wave * 576 + t * 16 + m16;
      const half8_t* kk = kbase + (size_t)col * 4;
      half8_t b1 = kk[quad & 1];
      half8_t b2 = kk[2 + (quad & 1)];
      floatx4 acc = {};
      acc = __builtin_amdgcn_mfma_f32_16x16x32_f16(A2, b2, acc, 0, 0, 0);
      acc = __builtin_amdgcn_mfma_f32_16x16x32_f16(A1, b1, acc, 0, 0, 0);
#pragma unroll
      for (int i = 0; i < 4; i++) {
        if (STORE) tBuf[wave][quad * 4 + i][tt * 16 + m16] = (_Float16)acc[i];
        float e = __expf(acc[i]);
        s[i] += e;
        u[i] = fmaf(acc[i], e, u[i]);
      }
    }
    if (STORE) {
      __syncthreads();
      int rb = lane >> 3, seg = lane & 7;
#pragma unroll
      for (int it = 0; it < 2; it++) {
        int rr = it * 8 + rb;
        uint4 vv = *(const uint4*)&tBuf[wave][rr][seg * 8];
        *(uint4*)(lgH + ((size_t)bh * 2304 + row0 + rr) * 2304 + wave * 576 +
                  g * 64 + seg * 8) = vv;
      }
      __syncthreads();
    }
  }
#pragma unroll
  for (int off = 1; off < 16; off <<= 1) {
#pragma unroll
    for (int i = 0; i < 4; i++) {
      s[i] += __shfl_xor(s[i], off);
      u[i] += __shfl_xor(u[i], off);
    }
  }
  if (m16 == 0) {
#pragma unroll
    for (int i = 0; i < 4; i++) {
      sWv[wave][quad * 4 + i] = s[i];
      uWv[wave][quad * 4 + i] = u[i];
    }
  }
  __syncthreads();
  if (tid < 16) {
    float S = sWv[0][tid] + sWv[1][tid] + sWv[2][tid] + sWv[3][tid];
    float U = uWv[0][tid] + uWv[1][tid] + uWv[2][tid] + uWv[3][tid];
    float er = __logf(S) - U / S;
    er += __shfl_xor(er, 1);
    er += __shfl_xor(er, 2);
    er += __shfl_xor(er, 4);
    er += __shfl_xor(er, 8);
    if (tid == 0) atomicAdd(&ent[bh], er);
  }
}

// K4: FUSED per-8-row-tile attention: QK^T MFMA -> LDS logit tile
// (stride 2320 halves = 4640B: rows bank-staggered) -> per-row top-k
// (packed radix histogram, 1 row/wave) -> in-place masked exp -> PV MFMA
// (legacy 4x576 j-split per 4-row group) -> oh. grid = 2304 (bh = blk&7
// for XCD L2 affinity; 2304/768 co-resident = 3 clean rounds), 512 thr,
// LDS 43.3KB -> 3 blocks/CU.
__global__ __launch_bounds__(512, 6) void k_attn_f(
    const _Float16* __restrict__ q2, const _Float16* __restrict__ k2,
    const _Float16* __restrict__ vt, const float* __restrict__ ent,
    const float* __restrict__ Wg1, const float* __restrict__ bg1,
    const float* __restrict__ Wg2, const float* __restrict__ bg2,
    float* __restrict__ oh) {
  __shared__ __align__(16) _Float16 lg[8 * 2320];  // 37120 B
  __shared__ unsigned hist[8][128];                // 4096 B
  __shared__ float sS[8];
  __shared__ __align__(16) float redSh[8][64];     // 2048 B

  int blk = blockIdx.x;
  int bh = blk & 7;     // one bh per XCD -> q2/k2/vt slices L2-resident
  int tile = blk >> 3;  // 0..287
  int row0 = tile * 8;
  int tid = threadIdx.x, lane = tid & 63, wave = tid >> 6;
  int m16 = lane & 15, quad = lane >> 4;

  // ---- gate MLP (uniform) ----
  float eAvg = ent[bh] * (1.f / 2304.f);
  float gacc = bg2[0];
#pragma unroll
  for (int i = 0; i < 16; i++) {
    float h = fmaxf(fmaf(eAvg, Wg1[i], bg1[i]), 0.f);
    gacc = fmaf(h, Wg2[i], gacc);
  }
  float ratio = 0.9f / (1.f + __expf(-gacc)) + 0.1f;
  int kp = (int)ceilf(ratio * 2304.f);
  unsigned keep = (unsigned)min(max(kp, 1), 2304);

  // ---- phase 1: QK^T -> lg rows 0..7 (A rows 8-15 duplicate 0-7) ----
  {
    const half8_t* q2v =
        (const half8_t*)(q2 + ((size_t)bh * 2304 + row0 + (m16 & 7)) * 32);
    half8_t A1 = q2v[quad];
    half8_t zh = {};
    half8_t A2 = (lane < 32) ? A1 : zh;
    const half8_t* kbase = (const half8_t*)(k2 + (size_t)bh * 2304 * 32);
#pragma unroll 2
    for (int t = 0; t < 18; t++) {
      int col = wave * 288 + t * 16 + m16;
      const half8_t* kk = kbase + (size_t)col * 4;
      half8_t b1 = kk[quad & 1];
      half8_t b2 = kk[2 + (quad & 1)];
      floatx4 acc = {};
      acc = __builtin_amdgcn_mfma_f32_16x16x32_f16(A2, b2, acc, 0, 0, 0);
      acc = __builtin_amdgcn_mfma_f32_16x16x32_f16(A1, b1, acc, 0, 0, 0);
      if (quad < 2) {  // D rows 0-7 unique; 8-15 are duplicates
#pragma unroll
        for (int i = 0; i < 4; i++)
          lg[(quad * 4 + i) * 2320 + col] = (_Float16)acc[i];
      }
    }
  }
  __syncthreads();

  // ---- phase 2: per-row top-k + in-place masked exp (1 row/wave) ----
  {
    char* rb = (char*)lg + wave * 4640;
    const uint4* s4 = (const uint4*)rb;
    uint4 q0 = s4[lane];
    uint4 q1 = s4[lane + 64];
    uint4 q2r = s4[lane + 128];
    uint4 q3 = s4[lane + 192];
    uint2 q4 = *(const uint2*)(rb + 4096 + lane * 8);
    unsigned wb[18] = {q0.x, q0.y, q0.z, q0.w, q1.x, q1.y, q1.z, q1.w,
                       q2r.x, q2r.y, q2r.z, q2r.w, q3.x, q3.y, q3.z, q3.w,
                       q4.x, q4.y};
    // packed ascending-key transform (2 f16 keys per word)
    unsigned kb[18];
#pragma unroll
    for (int i = 0; i < 18; i++)
      kb[i] = wb[i] ^ (((wb[i] >> 15) & 0x00010001u) * 0x7FFFu + 0x80008000u);

    unsigned* h = hist[wave];
    h[lane] = 0u;
    h[lane + 64] = 0u;
#pragma unroll
    for (int i = 0; i < 18; i++) {
      unsigned b1 = (kb[i] >> 8) & 0xFFu;
      unsigned b2 = kb[i] >> 24;
      atomicAdd(&h[b1 >> 1], 1u << ((b1 & 1) << 4));
      atomicAdd(&h[b2 >> 1], 1u << ((b2 & 1) << 4));
    }
    uint2 s1 = hist_select_p(h, lane, keep);
    unsigned B = s1.x;
    unsigned keep2 = keep - s1.y;  // rank within bucket B, >= 1

    h[lane] = 0u;
    h[lane + 64] = 0u;
#pragma unroll
    for (int i = 0; i < 18; i++) {
      unsigned klo = kb[i] & 0xFFFFu;
      unsigned khi = kb[i] >> 16;
      if ((klo >> 8) == B) {
        unsigned lb = klo & 0xFFu;
        atomicAdd(&h[lb >> 1], 1u << ((lb & 1) << 4));
      }
      if ((khi >> 8) == B) {
        unsigned lb = khi & 0xFFu;
        atomicAdd(&h[lb >> 1], 1u << ((lb & 1) << 4));
      }
    }
    uint2 s2 = hist_select_p(h, lane, keep2);
    _Float16 th_h = key_h((B << 8) | s2.x);

    // masked exp, pack f16, write back in place (legacy sp pairing)
    float sp = 0.f;
    uint4* prow4 = (uint4*)rb;
#pragma unroll
    for (int g = 0; g < 4; g++) {
      uint4 o;
      unsigned ow[4];
#pragma unroll
      for (int wj = 0; wj < 4; wj++) {
        unsigned w = wb[g * 4 + wj];
        _Float16 hlo = ubits_h((unsigned short)(w & 0xFFFFu));
        _Float16 hhi = ubits_h((unsigned short)(w >> 16));
        float plo = (hlo >= th_h) ? __expf((float)hlo) : 0.f;
        float phi = (hhi >= th_h) ? __expf((float)hhi) : 0.f;
        __half2 hp = __floats2half2_rn(plo, phi);
        ow[wj] = *(unsigned*)&hp;
        if (wj == 0) sp += ((plo + phi));
      }
      // legacy pairing: ((p0+p1)+(p2+p3)) + ((p4+p5)+(p6+p7))
      o.x = ow[0]; o.y = ow[1]; o.z = ow[2]; o.w = ow[3];
      prow4[lane + g * 64] = o;
      {
        _Float16 h2a = ubits_h((unsigned short)(wb[g * 4 + 1] & 0xFFFFu));
        _Float16 h2b = ubits_h((unsigned short)(wb[g * 4 + 1] >> 16));
        _Float16 h3a = ubits_h((unsigned short)(wb[g * 4 + 2] & 0xFFFFu));
        _Float16 h3b = ubits_h((unsigned short)(wb[g * 4 + 2] >> 16));
        _Float16 h4a = ubits_h((unsigned short)(wb[g * 4 + 3] & 0xFFFFu));
        _Float16 h4b = ubits_h((unsigned short)(wb[g * 4 + 3] >> 16));
        float p2 = (h2a >= th_h) ? __expf((float)h2a) : 0.f;
        float p3 = (h2b >= th_h) ? __expf((float)h2b) : 0.f;
        float p4 = (h3a >= th_h) ? __expf((float)h3a) : 0.f;
        float p5 = (h3b >= th_h) ? __expf((float)h3b) : 0.f;
        float p6 = (h4a >= th_h) ? __expf((float)h4a) : 0.f;
        float p7 = (h4b >= th_h) ? __expf((float)h4b) : 0.f;
        sp += (p2 + p3);
        sp += (p4 + p5) + (p6 + p7);
      }
    }
    {
      _Float16 h0 = ubits_h((unsigned short)(wb[16] & 0xFFFFu));
      _Float16 h1 = ubits_h((unsigned short)(wb[16] >> 16));
      _Float16 h2 = ubits_h((unsigned short)(wb[17] & 0xFFFFu));
      _Float16 h3 = ubits_h((unsigned short)(wb[17] >> 16));
      float p0 = (h0 >= th_h) ? __expf((float)h0) : 0.f;
      float p1 = (h1 >= th_h) ? __expf((float)h1) : 0.f;
      float p2 = (h2 >= th_h) ? __expf((float)h2) : 0.f;
      float p3 = (h3 >= th_h) ? __expf((float)h3) : 0.f;
      sp += (p0 + p1) + (p2 + p3);
      uint2 o;
      __half2 hp0 = __floats2half2_rn(p0, p1); o.x = *(unsigned*)&hp0;
      __half2 hp1 = __floats2half2_rn(p2, p3); o.y = *(unsigned*)&hp1;
      *(uint2*)(rb + 4096 + lane * 8) = o;
    }
#pragma unroll
    for (int off = 1; off < 64; off <<= 1) sp += __shfl_xor(sp, off);
    if (lane == 0) sS[wave] = sp;
  }
  __syncthreads();  // all rows' p visible; sS visible

  // ---- phase 3: PV via MFMA; wave = group*4 + j-quarter (legacy) ----
  {
    int g = wave >> 2;  // row group: rows g*4..g*4+3
    int jq = wave & 3;  // 576-col quarter
    const _Float16* vrow = vt + ((size_t)bh * 16 + m16) * 2304;
    const _Float16* prow = lg + (size_t)(g * 4 + (m16 & 3)) * 2320;
    int jb0 = jq * 576 + quad * 8;
    floatx4 acc = {};
#pragma unroll 6
    for (int t = 0; t < 18; t++) {
      int jb = jb0 + t * 32;
      half8_t a2 = *(const half8_t*)&prow[jb];
      half8_t b2 = *(const half8_t*)&vrow[jb];
      acc = __builtin_amdgcn_mfma_f32_16x16x32_f16(a2, b2, acc, 0, 0, 0);
    }
    if (lane < 16) {  // quad 0: D rows 0-3 = group rows, col = m16 = d
      *(floatx4*)&redSh[wave][m16 * 4] = acc;
    }
  }
  __syncthreads();
  if (tid < 128) {
    int g = tid >> 6, idx = tid & 63;
    int r = idx & 3, d = idx >> 2;
    float s2 = redSh[g * 4 + 0][d * 4 + r] + redSh[g * 4 + 1][d * 4 + r] +
               redSh[g * 4 + 2][d * 4 + r] + redSh[g * 4 + 3][d * 4 + r];
    oh[((size_t)(bh * 2304 + row0 + g * 4 + r)) * 16 + d] =
        s2 / sS[g * 4 + r];
  }
}

// K6: output projection, 4 output channels per block. grid = 2*16*9 = 288.
__global__ __launch_bounds__(256) void k_proj(const float* __restrict__ oh,
                                              const float* __restrict__ Wp,
                                              const float* __restrict__ bp,
                                              float* __restrict__ out) {
  int blk = blockIdx.x;
  int chunk = blk % 9;
  int cog = (blk / 9) % 16;
  int b = blk / (9 * 16);
  int co0 = cog * 4;
  int pos = chunk * 256 + threadIdx.x;
  float a0 = bp[co0 + 0], a1 = bp[co0 + 1], a2 = bp[co0 + 2], a3 = bp[co0 + 3];
#pragma unroll
  for (int head = 0; head < 4; head++) {
    const float4* op =
        (const float4*)(oh + ((size_t)((b * 4 + head) * 2304 + pos)) * 16);
#pragma unroll
    for (int p = 0; p < 4; p++) {
      float4 o4 = op[p];
#pragma unroll
      for (int i = 0; i < 4; i++) {
        const float* wr = Wp + (co0 + i) * 64 + head * 16 + p * 4;
        float* ai = (i == 0) ? &a0 : ((i == 1) ? &a1 : ((i == 2) ? &a2 : &a3));
        *ai = fmaf(wr[0], o4.x, *ai);
        *ai = fmaf(wr[1], o4.y, *ai);
        *ai = fmaf(wr[2], o4.z, *ai);
        *ai = fmaf(wr[3], o4.w, *ai);
      }
    }
  }
  out[(b * 64 + co0 + 0) * 2304 + pos] = a0;
  out[(b * 64 + co0 + 1) * 2304 + pos] = a1;
  out[(b * 64 + co0 + 2) * 2304 + pos] = a2;
  out[(b * 64 + co0 + 3) * 2304 + pos] = a3;
}

extern "C" void kernel_launch(void* const* d_in, const int* in_sizes, int n_in,
                              void* d_out, int out_size, void* d_ws,
                              size_t ws_size, hipStream_t stream) {
  const float* x    = (const float*)d_in[0];
  const float* Wqkv = (const float*)d_in[1];
  const float* bqkv = (const float*)d_in[2];
  const float* Wpos = (const float*)d_in[3];
  const float* bpos = (const float*)d_in[4];
  const float* Wg1  = (const float*)d_in[5];
  const float* bg1  = (const float*)d_in[6];
  const float* Wg2  = (const float*)d_in[7];
  const float* bg2  = (const float*)d_in[8];
  const float* Wpr  = (const float*)d_in[9];
  const float* bpr  = (const float*)d_in[10];
  float* out = (float*)d_out;

  // workspace (no logit cache)
  char* base = (char*)d_ws;
  float* qkv_raw = (float*)base;        // 884736 floats
  float* oh = qkv_raw + 884736;         // 294912 floats
  float* ent = oh + 294912;             // 8 floats
  _Float16* q2 = (_Float16*)(ent + 8);  // 589824 halves
  _Float16* k2 = q2 + 589824;           // 589824 halves
  _Float16* vt = k2 + 589824;           // 294912 halves (V^T f16 [bh][d][j])

  hipLaunchKernelGGL(k_qkv, dim3(2 * 48 * 9), dim3(256), 0, stream,
                     x, Wqkv, bqkv, qkv_raw, ent);
  hipLaunchKernelGGL(k_dw, dim3(432), dim3(256), 0, stream,
                     qkv_raw, Wpos, bpos, q2, k2, vt);
  hipLaunchKernelGGL((k_ent_t<false>), dim3(8 * 144), dim3(256), 0, stream,
                     q2, k2, ent, (_Float16*)nullptr);
  hipLaunchKernelGGL(k_attn_f, dim3(2304), dim3(512), 0, stream,
                     q2, k2, vt, ent, Wg1, bg1, Wg2, bg2, oh);
  hipLaunchKernelGGL(k_proj, dim3(2 * 16 * 9), dim3(256), 0, stream,
                     oh, Wpr, bpr, out);
}

// Round 6
// 228.384 us; speedup vs baseline: 1.0045x; 1.0045x over previous
//
#include <hip/hip_runtime.h>
#include <hip/hip_fp16.h>

// b=2, c=64, 48x48 -> n=2304, heads=4, hd=16. n = 9*256 = 144*16.
// r23: fused cache-free attention, 8-row tiles, ballot-search top-k.
// History: r18-r20 proved top-k ALU wasn't the wall in the split kernel
// (HBM cache read was); r21 fused QK^T+topk+PV (FETCH 44MB->1.5MB) but
// LDS histogram top-k SERIALIZES on same-address atomics (concentrated
// logit distribution: 2304 increments into ~20 of 256 buckets; 8.6-8.9M
// SQ_LDS_BANK_CONFLICT cycles in r21/r22, exposed with no HBM stall to
// hide under -- in r20's split kernel the same histogram hid under HBM
// latency). r23 keeps the fused structure and swaps phase 2 to the
// ATOMIC-FREE ballot bit-search in integer key domain (keys unpacked to
// 36 u32 regs; 16 rounds x 36 v_cmp+popcount, SALU accumulate, uniform
// branch; zero LDS ops). hist[] deleted -> LDS 39.2KB (4 blocks/CU if
// VGPR<=64). Output bit-path preserved: selection semantics identical
// to r20-r22 (integer count, f16 mask), exp/sp pairing + PV 4x576
// j-split + reduce order verbatim. SEPARATE k_proj (r17: fused atomic
// projection 60->94us - do not revisit). k_dw: 432 blocks (r17-kept).

typedef _Float16 half8_t __attribute__((ext_vector_type(8)));
typedef float floatx4 __attribute__((ext_vector_type(4)));

union HU { unsigned short s; _Float16 h; };
__device__ __forceinline__ _Float16 ubits_h(unsigned short u) {
  HU c; c.s = u; return c.h;
}
// ascending 16-bit key -> the f16 value it encodes
__device__ __forceinline__ _Float16 key_h(unsigned k) {
  unsigned short u = (k & 0x8000u) ? (unsigned short)(k & 0x7FFFu)
                                   : (unsigned short)((~k) & 0xFFFFu);
  return ubits_h(u);
}

// K1: 1x1 conv, 4 output channels per block. grid = 2*48*9 = 864;
// also zeroes ent[] (replaces memset dispatch).
__global__ __launch_bounds__(256) void k_qkv(const float* __restrict__ x,
                                             const float* __restrict__ W,
                                             const float* __restrict__ bias,
                                             float* __restrict__ out,
                                             float* __restrict__ ent) {
  if (blockIdx.x == 0 && threadIdx.x < 8) ent[threadIdx.x] = 0.f;
  int blk = blockIdx.x;
  int chunk = blk % 9;
  int og = (blk / 9) % 48;
  int b = blk / (9 * 48);
  int o0 = og * 4;
  int pos = chunk * 256 + threadIdx.x;
  const float* xb = x + b * 64 * 2304 + pos;
  const float* w0 = W + (o0 + 0) * 64;
  const float* w1 = W + (o0 + 1) * 64;
  const float* w2 = W + (o0 + 2) * 64;
  const float* w3 = W + (o0 + 3) * 64;
  float a0 = bias[o0 + 0], a1 = bias[o0 + 1];
  float a2 = bias[o0 + 2], a3 = bias[o0 + 3];
#pragma unroll
  for (int c = 0; c < 64; c++) {
    float xv = xb[c * 2304];
    a0 = fmaf(w0[c], xv, a0);
    a1 = fmaf(w1[c], xv, a1);
    a2 = fmaf(w2[c], xv, a2);
    a3 = fmaf(w3[c], xv, a3);
  }
  out[(b * 192 + o0 + 0) * 2304 + pos] = a0;
  out[(b * 192 + o0 + 1) * 2304 + pos] = a1;
  out[(b * 192 + o0 + 2) * 2304 + pos] = a2;
  out[(b * 192 + o0 + 3) * 2304 + pos] = a3;
}

// K2: 3x3 depthwise conv, 8 channels per block with LDS staging; q/k
// packed per-row-half stores (2x 16B contiguous). grid = 432.
__global__ __launch_bounds__(256) void k_dw(const float* __restrict__ qkv,
                                            const float* __restrict__ Wpos,
                                            const float* __restrict__ bpos,
                                            _Float16* __restrict__ q2,
                                            _Float16* __restrict__ k2,
                                            _Float16* __restrict__ vt) {
  __shared__ float smem[8][384];  // 8 ch x 8 rows x 48 = 12.3 KB
  int blk = blockIdx.x;
  int chunk = blk % 9;
  int half = (blk / 9) % 2;
  int sel = (blk / 18) % 3;
  int head = (blk / 54) % 4;
  int b = blk / 216;
  int chbase = sel * 64 + head * 16 + half * 8;
  int bh = b * 4 + head;
  int tid = threadIdx.x;
  int p0 = chunk * 256;
  int baserow = p0 / 48;
  int rA = min(max(baserow - 1, 0), 40);  // 8-row window within [0,47]

  const float* src = qkv + (size_t)(b * 192 + chbase) * 2304;
#pragma unroll
  for (int l = 0; l < 12; l++) {
    int idx = tid + l * 256;
    int ch = idx / 384;
    int off = idx - ch * 384;
    int rr = off / 48;
    int cc = off - rr * 48;
    smem[ch][off] = src[(size_t)ch * 2304 + (rA + rr) * 48 + cc];
  }
  __syncthreads();

  int pos = p0 + tid;
  int yy = pos / 48, xx = pos - yy * 48;
  int ry = yy - rA;
  float accv[8];
#pragma unroll
  for (int d = 0; d < 8; d++) {
    const float* w = Wpos + (chbase + d) * 9;
    float a = bpos[chbase + d];
#pragma unroll
    for (int dy = -1; dy <= 1; dy++) {
      int y2 = yy + dy;
      if ((unsigned)y2 < 48u) {
#pragma unroll
        for (int dx = -1; dx <= 1; dx++) {
          int x2 = xx + dx;
          if ((unsigned)x2 < 48u)
            a = fmaf(w[(dy + 1) * 3 + (dx + 1)], smem[d][(ry + dy) * 48 + x2],
                     a);
        }
      }
    }
    accv[d] = a;
  }

  if (sel == 2) {
#pragma unroll
    for (int d = 0; d < 8; d++)
      vt[((size_t)bh * 16 + half * 8 + d) * 2304 + pos] = (_Float16)accv[d];
  } else {
    _Float16 h1[8], h2[8];
#pragma unroll
    for (int d = 0; d < 8; d++) {
      float a = (sel == 0) ? accv[d] * 0.25f : accv[d];
      h1[d] = (_Float16)a;
      h2[d] = (_Float16)(a - (float)h1[d]);
    }
    _Float16* dst = ((sel == 0) ? q2 : k2) + ((size_t)bh * 2304 + pos) * 32;
    *(uint4*)(dst + half * 8) = *(uint4*)&h1[0];
    *(uint4*)(dst + 16 + half * 8) = *(uint4*)&h2[0];
  }
}

// K3: SINGLE-PASS MFMA QK^T: entropy sums (shift-invariant, no max).
// STORE=false: no logit store, no barriers. grid = 8*144, 256 thr.
template <bool STORE>
__global__ __launch_bounds__(256) void k_ent_t(const _Float16* __restrict__ q2,
                                               const _Float16* __restrict__ k2,
                                               float* __restrict__ ent,
                                               _Float16* __restrict__ lgH) {
  __shared__ __align__(16) _Float16 tBuf[4][16][72];
  __shared__ float sWv[4][16], uWv[4][16];

  int blk = blockIdx.x;
  int rowtile = blk % 144;
  int bh = blk / 144;
  int row0 = rowtile * 16;
  int tid = threadIdx.x, lane = tid & 63, wave = tid >> 6;
  int m16 = lane & 15, quad = lane >> 4;

  const half8_t* q2v =
      (const half8_t*)(q2 + ((size_t)bh * 2304 + row0 + m16) * 32);
  half8_t A1 = q2v[quad];
  half8_t zh = {};
  half8_t A2 = (lane < 32) ? A1 : zh;
  const half8_t* kbase = (const half8_t*)(k2 + (size_t)bh * 2304 * 32);

  // s0 = sum e^a, u0 = sum a e^a  (entropy = log s0 - u0/s0; shift-inv.)
  float s[4] = {0.f, 0.f, 0.f, 0.f}, u[4] = {0.f, 0.f, 0.f, 0.f};
  for (int g = 0; g < 9; g++) {
#pragma unroll
    for (int tt = 0; tt < 4; tt++) {
      int t = g * 4 + tt;
      int col = wave * 576 + t * 16 + m16;
      const half8_t* kk = kbase + (size_t)col * 4;
      half8_t b1 = kk[quad & 1];
      half8_t b2 = kk[2 + (quad & 1)];
      floatx4 acc = {};
      acc = __builtin_amdgcn_mfma_f32_16x16x32_f16(A2, b2, acc, 0, 0, 0);
      acc = __builtin_amdgcn_mfma_f32_16x16x32_f16(A1, b1, acc, 0, 0, 0);
#pragma unroll
      for (int i = 0; i < 4; i++) {
        if (STORE) tBuf[wave][quad * 4 + i][tt * 16 + m16] = (_Float16)acc[i];
        float e = __expf(acc[i]);
        s[i] += e;
        u[i] = fmaf(acc[i], e, u[i]);
      }
    }
    if (STORE) {
      __syncthreads();
      int rb = lane >> 3, seg = lane & 7;
#pragma unroll
      for (int it = 0; it < 2; it++) {
        int rr = it * 8 + rb;
        uint4 vv = *(const uint4*)&tBuf[wave][rr][seg * 8];
        *(uint4*)(lgH + ((size_t)bh * 2304 + row0 + rr) * 2304 + wave * 576 +
                  g * 64 + seg * 8) = vv;
      }
      __syncthreads();
    }
  }
#pragma unroll
  for (int off = 1; off < 16; off <<= 1) {
#pragma unroll
    for (int i = 0; i < 4; i++) {
      s[i] += __shfl_xor(s[i], off);
      u[i] += __shfl_xor(u[i], off);
    }
  }
  if (m16 == 0) {
#pragma unroll
    for (int i = 0; i < 4; i++) {
      sWv[wave][quad * 4 + i] = s[i];
      uWv[wave][quad * 4 + i] = u[i];
    }
  }
  __syncthreads();
  if (tid < 16) {
    float S = sWv[0][tid] + sWv[1][tid] + sWv[2][tid] + sWv[3][tid];
    float U = uWv[0][tid] + uWv[1][tid] + uWv[2][tid] + uWv[3][tid];
    float er = __logf(S) - U / S;
    er += __shfl_xor(er, 1);
    er += __shfl_xor(er, 2);
    er += __shfl_xor(er, 4);
    er += __shfl_xor(er, 8);
    if (tid == 0) atomicAdd(&ent[bh], er);
  }
}

// K4: FUSED per-8-row-tile attention: QK^T MFMA -> LDS logit tile
// (stride 2320 halves: rows bank-staggered) -> per-row top-k (ballot
// bit-search, integer keys in regs, NO LDS ops) -> in-place masked exp
// -> PV MFMA (legacy 4x576 j-split per 4-row group) -> oh. grid = 2304
// (bh = blk&7 for XCD L2 affinity), 512 thr. LDS 39.2KB.
__global__ __launch_bounds__(512, 6) void k_attn_f(
    const _Float16* __restrict__ q2, const _Float16* __restrict__ k2,
    const _Float16* __restrict__ vt, const float* __restrict__ ent,
    const float* __restrict__ Wg1, const float* __restrict__ bg1,
    const float* __restrict__ Wg2, const float* __restrict__ bg2,
    float* __restrict__ oh) {
  __shared__ __align__(16) _Float16 lg[8 * 2320];  // 37120 B
  __shared__ float sS[8];
  __shared__ __align__(16) float redSh[8][64];     // 2048 B

  int blk = blockIdx.x;
  int bh = blk & 7;     // one bh per XCD -> q2/k2/vt slices L2-resident
  int tile = blk >> 3;  // 0..287
  int row0 = tile * 8;
  int tid = threadIdx.x, lane = tid & 63, wave = tid >> 6;
  int m16 = lane & 15, quad = lane >> 4;

  // ---- gate MLP (uniform) ----
  float eAvg = ent[bh] * (1.f / 2304.f);
  float gacc = bg2[0];
#pragma unroll
  for (int i = 0; i < 16; i++) {
    float h = fmaxf(fmaf(eAvg, Wg1[i], bg1[i]), 0.f);
    gacc = fmaf(h, Wg2[i], gacc);
  }
  float ratio = 0.9f / (1.f + __expf(-gacc)) + 0.1f;
  int kp = (int)ceilf(ratio * 2304.f);
  unsigned keep = (unsigned)min(max(kp, 1), 2304);

  // ---- phase 1: QK^T -> lg rows 0..7 (A rows 8-15 duplicate 0-7) ----
  {
    const half8_t* q2v =
        (const half8_t*)(q2 + ((size_t)bh * 2304 + row0 + (m16 & 7)) * 32);
    half8_t A1 = q2v[quad];
    half8_t zh = {};
    half8_t A2 = (lane < 32) ? A1 : zh;
    const half8_t* kbase = (const half8_t*)(k2 + (size_t)bh * 2304 * 32);
#pragma unroll 2
    for (int t = 0; t < 18; t++) {
      int col = wave * 288 + t * 16 + m16;
      const half8_t* kk = kbase + (size_t)col * 4;
      half8_t b1 = kk[quad & 1];
      half8_t b2 = kk[2 + (quad & 1)];
      floatx4 acc = {};
      acc = __builtin_amdgcn_mfma_f32_16x16x32_f16(A2, b2, acc, 0, 0, 0);
      acc = __builtin_amdgcn_mfma_f32_16x16x32_f16(A1, b1, acc, 0, 0, 0);
      if (quad < 2) {  // D rows 0-7 unique; 8-15 are duplicates
#pragma unroll
        for (int i = 0; i < 4; i++)
          lg[(quad * 4 + i) * 2320 + col] = (_Float16)acc[i];
      }
    }
  }
  __syncthreads();

  // ---- phase 2: per-row top-k (ballot search) + masked exp ----
  {
    char* rb = (char*)lg + wave * 4640;
    const uint4* s4 = (const uint4*)rb;
    uint4 q0 = s4[lane];
    uint4 q1 = s4[lane + 64];
    uint4 q2r = s4[lane + 128];
    uint4 q3 = s4[lane + 192];
    uint2 q4 = *(const uint2*)(rb + 4096 + lane * 8);
    unsigned wb[18] = {q0.x, q0.y, q0.z, q0.w, q1.x, q1.y, q1.z, q1.w,
                       q2r.x, q2r.y, q2r.z, q2r.w, q3.x, q3.y, q3.z, q3.w,
                       q4.x, q4.y};
    // ascending-key transform (packed), then unpack to 36 u32 regs
    unsigned ku[36];
#pragma unroll
    for (int i = 0; i < 18; i++) {
      unsigned kbi =
          wb[i] ^ (((wb[i] >> 15) & 0x00010001u) * 0x7FFFu + 0x80008000u);
      ku[2 * i + 0] = kbi & 0xFFFFu;
      ku[2 * i + 1] = kbi >> 16;
    }

    // exact k-th largest: 16-round ballot bit-search, no LDS traffic
    unsigned T = 0u;
    for (int bit = 15; bit >= 0; --bit) {
      unsigned cand = T | (1u << bit);
      unsigned cnt = 0u;
#pragma unroll
      for (int i = 0; i < 36; i++)
        cnt += (unsigned)__popcll(__ballot(ku[i] >= cand));
      if (cnt >= keep) {
        T = cand;  // uniform
        if (cnt == keep) break;
      }
    }
    _Float16 th_h = key_h(T);

    // masked exp, pack f16, write back in place (legacy sp pairing)
    float sp = 0.f;
    uint4* prow4 = (uint4*)rb;
#pragma unroll
    for (int g = 0; g < 4; g++) {
      uint4 o;
      unsigned ow[4];
#pragma unroll
      for (int wj = 0; wj < 4; wj++) {
        unsigned w = wb[g * 4 + wj];
        _Float16 hlo = ubits_h((unsigned short)(w & 0xFFFFu));
        _Float16 hhi = ubits_h((unsigned short)(w >> 16));
        float plo = (hlo >= th_h) ? __expf((float)hlo) : 0.f;
        float phi = (hhi >= th_h) ? __expf((float)hhi) : 0.f;
        __half2 hp = __floats2half2_rn(plo, phi);
        ow[wj] = *(unsigned*)&hp;
        if (wj == 0) sp += ((plo + phi));
      }
      // legacy pairing: ((p0+p1)+(p2+p3)) + ((p4+p5)+(p6+p7))
      o.x = ow[0]; o.y = ow[1]; o.z = ow[2]; o.w = ow[3];
      prow4[lane + g * 64] = o;
      {
        _Float16 h2a = ubits_h((unsigned short)(wb[g * 4 + 1] & 0xFFFFu));
        _Float16 h2b = ubits_h((unsigned short)(wb[g * 4 + 1] >> 16));
        _Float16 h3a = ubits_h((unsigned short)(wb[g * 4 + 2] & 0xFFFFu));
        _Float16 h3b = ubits_h((unsigned short)(wb[g * 4 + 2] >> 16));
        _Float16 h4a = ubits_h((unsigned short)(wb[g * 4 + 3] & 0xFFFFu));
        _Float16 h4b = ubits_h((unsigned short)(wb[g * 4 + 3] >> 16));
        float p2 = (h2a >= th_h) ? __expf((float)h2a) : 0.f;
        float p3 = (h2b >= th_h) ? __expf((float)h2b) : 0.f;
        float p4 = (h3a >= th_h) ? __expf((float)h3a) : 0.f;
        float p5 = (h3b >= th_h) ? __expf((float)h3b) : 0.f;
        float p6 = (h4a >= th_h) ? __expf((float)h4a) : 0.f;
        float p7 = (h4b >= th_h) ? __expf((float)h4b) : 0.f;
        sp += (p2 + p3);
        sp += (p4 + p5) + (p6 + p7);
      }
    }
    {
      _Float16 h0 = ubits_h((unsigned short)(wb[16] & 0xFFFFu));
      _Float16 h1 = ubits_h((unsigned short)(wb[16] >> 16));
      _Float16 h2 = ubits_h((unsigned short)(wb[17] & 0xFFFFu));
      _Float16 h3 = ubits_h((unsigned short)(wb[17] >> 16));
      float p0 = (h0 >= th_h) ? __expf((float)h0) : 0.f;
      float p1 = (h1 >= th_h) ? __expf((float)h1) : 0.f;
      float p2 = (h2 >= th_h) ? __expf((float)h2) : 0.f;
      float p3 = (h3 >= th_h) ? __expf((float)h3) : 0.f;
      sp += (p0 + p1) + (p2 + p3);
      uint2 o;
      __half2 hp0 = __floats2half2_rn(p0, p1); o.x = *(unsigned*)&hp0;
      __half2 hp1 = __floats2half2_rn(p2, p3); o.y = *(unsigned*)&hp1;
      *(uint2*)(rb + 4096 + lane * 8) = o;
    }
#pragma unroll
    for (int off = 1; off < 64; off <<= 1) sp += __shfl_xor(sp, off);
    if (lane == 0) sS[wave] = sp;
  }
  __syncthreads();  // all rows' p visible; sS visible

  // ---- phase 3: PV via MFMA; wave = group*4 + j-quarter (legacy) ----
  {
    int g = wave >> 2;  // row group: rows g*4..g*4+3
    int jq = wave & 3;  // 576-col quarter
    const _Float16* vrow = vt + ((size_t)bh * 16 + m16) * 2304;
    const _Float16* prow = lg + (size_t)(g * 4 + (m16 & 3)) * 2320;
    int jb0 = jq * 576 + quad * 8;
    floatx4 acc = {};
#pragma unroll 6
    for (int t = 0; t < 18; t++) {
      int jb = jb0 + t * 32;
      half8_t a2 = *(const half8_t*)&prow[jb];
      half8_t b2 = *(const half8_t*)&vrow[jb];
      acc = __builtin_amdgcn_mfma_f32_16x16x32_f16(a2, b2, acc, 0, 0, 0);
    }
    if (lane < 16) {  // quad 0: D rows 0-3 = group rows, col = m16 = d
      *(floatx4*)&redSh[wave][m16 * 4] = acc;
    }
  }
  __syncthreads();
  if (tid < 128) {
    int g = tid >> 6, idx = tid & 63;
    int r = idx & 3, d = idx >> 2;
    float s2 = redSh[g * 4 + 0][d * 4 + r] + redSh[g * 4 + 1][d * 4 + r] +
               redSh[g * 4 + 2][d * 4 + r] + redSh[g * 4 + 3][d * 4 + r];
    oh[((size_t)(bh * 2304 + row0 + g * 4 + r)) * 16 + d] =
        s2 / sS[g * 4 + r];
  }
}

// K6: output projection, 4 output channels per block. grid = 2*16*9 = 288.
__global__ __launch_bounds__(256) void k_proj(const float* __restrict__ oh,
                                              const float* __restrict__ Wp,
                                              const float* __restrict__ bp,
                                              float* __restrict__ out) {
  int blk = blockIdx.x;
  int chunk = blk % 9;
  int cog = (blk / 9) % 16;
  int b = blk / (9 * 16);
  int co0 = cog * 4;
  int pos = chunk * 256 + threadIdx.x;
  float a0 = bp[co0 + 0], a1 = bp[co0 + 1], a2 = bp[co0 + 2], a3 = bp[co0 + 3];
#pragma unroll
  for (int head = 0; head < 4; head++) {
    const float4* op =
        (const float4*)(oh + ((size_t)((b * 4 + head) * 2304 + pos)) * 16);
#pragma unroll
    for (int p = 0; p < 4; p++) {
      float4 o4 = op[p];
#pragma unroll
      for (int i = 0; i < 4; i++) {
        const float* wr = Wp + (co0 + i) * 64 + head * 16 + p * 4;
        float* ai = (i == 0) ? &a0 : ((i == 1) ? &a1 : ((i == 2) ? &a2 : &a3));
        *ai = fmaf(wr[0], o4.x, *ai);
        *ai = fmaf(wr[1], o4.y, *ai);
        *ai = fmaf(wr[2], o4.z, *ai);
        *ai = fmaf(wr[3], o4.w, *ai);
      }
    }
  }
  out[(b * 64 + co0 + 0) * 2304 + pos] = a0;
  out[(b * 64 + co0 + 1) * 2304 + pos] = a1;
  out[(b * 64 + co0 + 2) * 2304 + pos] = a2;
  out[(b * 64 + co0 + 3) * 2304 + pos] = a3;
}

extern "C" void kernel_launch(void* const* d_in, const int* in_sizes, int n_in,
                              void* d_out, int out_size, void* d_ws,
                              size_t ws_size, hipStream_t stream) {
  const float* x    = (const float*)d_in[0];
  const float* Wqkv = (const float*)d_in[1];
  const float* bqkv = (const float*)d_in[2];
  const float* Wpos = (const float*)d_in[3];
  const float* bpos = (const float*)d_in[4];
  const float* Wg1  = (const float*)d_in[5];
  const float* bg1  = (const float*)d_in[6];
  const float* Wg2  = (const float*)d_in[7];
  const float* bg2  = (const float*)d_in[8];
  const float* Wpr  = (const float*)d_in[9];
  const float* bpr  = (const float*)d_in[10];
  float* out = (float*)d_out;

  // workspace (no logit cache)
  char* base = (char*)d_ws;
  float* qkv_raw = (float*)base;        // 884736 floats
  float* oh = qkv_raw + 884736;         // 294912 floats
  float* ent = oh + 294912;             // 8 floats
  _Float16* q2 = (_Float16*)(ent + 8);  // 589824 halves
  _Float16* k2 = q2 + 589824;           // 589824 halves
  _Float16* vt = k2 + 589824;           // 294912 halves (V^T f16 [bh][d][j])

  hipLaunchKernelGGL(k_qkv, dim3(2 * 48 * 9), dim3(256), 0, stream,
                     x, Wqkv, bqkv, qkv_raw, ent);
  hipLaunchKernelGGL(k_dw, dim3(432), dim3(256), 0, stream,
                     qkv_raw, Wpos, bpos, q2, k2, vt);
  hipLaunchKernelGGL((k_ent_t<false>), dim3(8 * 144), dim3(256), 0, stream,
                     q2, k2, ent, (_Float16*)nullptr);
  hipLaunchKernelGGL(k_attn_f, dim3(2304), dim3(512), 0, stream,
                     q2, k2, vt, ent, Wg1, bg1, Wg2, bg2, oh);
  hipLaunchKernelGGL(k_proj, dim3(2 * 16 * 9), dim3(256), 0, stream,
                     oh, Wpr, bpr, out);
}

// Round 7
// 208.548 us; speedup vs baseline: 1.1000x; 1.0951x over previous
//
#include <hip/hip_runtime.h>
#include <hip/hip_fp16.h>

// b=2, c=64, 48x48 -> n=2304, heads=4, hd=16. n = 9*256 = 144*16.
// r24: fused cache-free attention, 16-ROW tiles + ballot search.
// Cross-round evidence: r4(16-row,hist)=86us; r5(8-row,hist)=113;
// r6(8-row,ballot)=110.7 with conflicts 8.9M->1.3M and NO time change
// => neither atomics nor ballot ALU was the wall; 8-row DOUBLED
// phase-1 (MFMA + 147KB/block k2 L2 re-read -> 340MB) and phase-3 vt
// re-reads (340MB). r24: 16-row (1152 blocks) halves k2 traffic,
// quarters vt traffic; ballot search (atomic-free, r6 code verbatim,
// 2 rows/wave); row stride 2328 halves (rows 12 banks apart, quad-rows
// 16 apart -- r4's 4-way store conflict gone); launch_bounds(512,4)
// raises VGPR budget to 128 so wb[18]+ku[36] stay in arch VGPRs (r6:
// VGPR=32 forced AGPR round-trips, ~72 extra issue-cyc/round/wave; LDS
// already caps at 2 blocks/CU so no occupancy cost). Output bit-path
// preserved: phase-2 search/exp per-row code identical to r6; phase-3
// = r4's verified 4-wave j-quarter PV + reduce. SEPARATE k_proj (r17:
// fused atomic projection 60->94us - do not revisit).

typedef _Float16 half8_t __attribute__((ext_vector_type(8)));
typedef float floatx4 __attribute__((ext_vector_type(4)));

#define LSTR 2328  // lg row stride in halves (4656B; 1164 dw = 12 mod 32)

union HU { unsigned short s; _Float16 h; };
__device__ __forceinline__ _Float16 ubits_h(unsigned short u) {
  HU c; c.s = u; return c.h;
}
// ascending 16-bit key -> the f16 value it encodes
__device__ __forceinline__ _Float16 key_h(unsigned k) {
  unsigned short u = (k & 0x8000u) ? (unsigned short)(k & 0x7FFFu)
                                   : (unsigned short)((~k) & 0xFFFFu);
  return ubits_h(u);
}

// K1: 1x1 conv, 4 output channels per block. grid = 2*48*9 = 864;
// also zeroes ent[] (replaces memset dispatch).
__global__ __launch_bounds__(256) void k_qkv(const float* __restrict__ x,
                                             const float* __restrict__ W,
                                             const float* __restrict__ bias,
                                             float* __restrict__ out,
                                             float* __restrict__ ent) {
  if (blockIdx.x == 0 && threadIdx.x < 8) ent[threadIdx.x] = 0.f;
  int blk = blockIdx.x;
  int chunk = blk % 9;
  int og = (blk / 9) % 48;
  int b = blk / (9 * 48);
  int o0 = og * 4;
  int pos = chunk * 256 + threadIdx.x;
  const float* xb = x + b * 64 * 2304 + pos;
  const float* w0 = W + (o0 + 0) * 64;
  const float* w1 = W + (o0 + 1) * 64;
  const float* w2 = W + (o0 + 2) * 64;
  const float* w3 = W + (o0 + 3) * 64;
  float a0 = bias[o0 + 0], a1 = bias[o0 + 1];
  float a2 = bias[o0 + 2], a3 = bias[o0 + 3];
#pragma unroll
  for (int c = 0; c < 64; c++) {
    float xv = xb[c * 2304];
    a0 = fmaf(w0[c], xv, a0);
    a1 = fmaf(w1[c], xv, a1);
    a2 = fmaf(w2[c], xv, a2);
    a3 = fmaf(w3[c], xv, a3);
  }
  out[(b * 192 + o0 + 0) * 2304 + pos] = a0;
  out[(b * 192 + o0 + 1) * 2304 + pos] = a1;
  out[(b * 192 + o0 + 2) * 2304 + pos] = a2;
  out[(b * 192 + o0 + 3) * 2304 + pos] = a3;
}

// K2: 3x3 depthwise conv, 8 channels per block with LDS staging; q/k
// packed per-row-half stores (2x 16B contiguous). grid = 432.
__global__ __launch_bounds__(256) void k_dw(const float* __restrict__ qkv,
                                            const float* __restrict__ Wpos,
                                            const float* __restrict__ bpos,
                                            _Float16* __restrict__ q2,
                                            _Float16* __restrict__ k2,
                                            _Float16* __restrict__ vt) {
  __shared__ float smem[8][384];  // 8 ch x 8 rows x 48 = 12.3 KB
  int blk = blockIdx.x;
  int chunk = blk % 9;
  int half = (blk / 9) % 2;
  int sel = (blk / 18) % 3;
  int head = (blk / 54) % 4;
  int b = blk / 216;
  int chbase = sel * 64 + head * 16 + half * 8;
  int bh = b * 4 + head;
  int tid = threadIdx.x;
  int p0 = chunk * 256;
  int baserow = p0 / 48;
  int rA = min(max(baserow - 1, 0), 40);  // 8-row window within [0,47]

  const float* src = qkv + (size_t)(b * 192 + chbase) * 2304;
#pragma unroll
  for (int l = 0; l < 12; l++) {
    int idx = tid + l * 256;
    int ch = idx / 384;
    int off = idx - ch * 384;
    int rr = off / 48;
    int cc = off - rr * 48;
    smem[ch][off] = src[(size_t)ch * 2304 + (rA + rr) * 48 + cc];
  }
  __syncthreads();

  int pos = p0 + tid;
  int yy = pos / 48, xx = pos - yy * 48;
  int ry = yy - rA;
  float accv[8];
#pragma unroll
  for (int d = 0; d < 8; d++) {
    const float* w = Wpos + (chbase + d) * 9;
    float a = bpos[chbase + d];
#pragma unroll
    for (int dy = -1; dy <= 1; dy++) {
      int y2 = yy + dy;
      if ((unsigned)y2 < 48u) {
#pragma unroll
        for (int dx = -1; dx <= 1; dx++) {
          int x2 = xx + dx;
          if ((unsigned)x2 < 48u)
            a = fmaf(w[(dy + 1) * 3 + (dx + 1)], smem[d][(ry + dy) * 48 + x2],
                     a);
        }
      }
    }
    accv[d] = a;
  }

  if (sel == 2) {
#pragma unroll
    for (int d = 0; d < 8; d++)
      vt[((size_t)bh * 16 + half * 8 + d) * 2304 + pos] = (_Float16)accv[d];
  } else {
    _Float16 h1[8], h2[8];
#pragma unroll
    for (int d = 0; d < 8; d++) {
      float a = (sel == 0) ? accv[d] * 0.25f : accv[d];
      h1[d] = (_Float16)a;
      h2[d] = (_Float16)(a - (float)h1[d]);
    }
    _Float16* dst = ((sel == 0) ? q2 : k2) + ((size_t)bh * 2304 + pos) * 32;
    *(uint4*)(dst + half * 8) = *(uint4*)&h1[0];
    *(uint4*)(dst + 16 + half * 8) = *(uint4*)&h2[0];
  }
}

// K3: SINGLE-PASS MFMA QK^T: entropy sums (shift-invariant, no max).
// STORE=false: no logit store, no barriers. grid = 8*144, 256 thr.
template <bool STORE>
__global__ __launch_bounds__(256) void k_ent_t(const _Float16* __restrict__ q2,
                                               const _Float16* __restrict__ k2,
                                               float* __restrict__ ent,
                                               _Float16* __restrict__ lgH) {
  __shared__ __align__(16) _Float16 tBuf[4][16][72];
  __shared__ float sWv[4][16], uWv[4][16];

  int blk = blockIdx.x;
  int rowtile = blk % 144;
  int bh = blk / 144;
  int row0 = rowtile * 16;
  int tid = threadIdx.x, lane = tid & 63, wave = tid >> 6;
  int m16 = lane & 15, quad = lane >> 4;

  const half8_t* q2v =
      (const half8_t*)(q2 + ((size_t)bh * 2304 + row0 + m16) * 32);
  half8_t A1 = q2v[quad];
  half8_t zh = {};
  half8_t A2 = (lane < 32) ? A1 : zh;
  const half8_t* kbase = (const half8_t*)(k2 + (size_t)bh * 2304 * 32);

  // s0 = sum e^a, u0 = sum a e^a  (entropy = log s0 - u0/s0; shift-inv.)
  float s[4] = {0.f, 0.f, 0.f, 0.f}, u[4] = {0.f, 0.f, 0.f, 0.f};
  for (int g = 0; g < 9; g++) {
#pragma unroll
    for (int tt = 0; tt < 4; tt++) {
      int t = g * 4 + tt;
      int col = wave * 576 + t * 16 + m16;
      const half8_t* kk = kbase + (size_t)col * 4;
      half8_t b1 = kk[quad & 1];
      half8_t b2 = kk[2 + (quad & 1)];
      floatx4 acc = {};
      acc = __builtin_amdgcn_mfma_f32_16x16x32_f16(A2, b2, acc, 0, 0, 0);
      acc = __builtin_amdgcn_mfma_f32_16x16x32_f16(A1, b1, acc, 0, 0, 0);
#pragma unroll
      for (int i = 0; i < 4; i++) {
        if (STORE) tBuf[wave][quad * 4 + i][tt * 16 + m16] = (_Float16)acc[i];
        float e = __expf(acc[i]);
        s[i] += e;
        u[i] = fmaf(acc[i], e, u[i]);
      }
    }
    if (STORE) {
      __syncthreads();
      int rb = lane >> 3, seg = lane & 7;
#pragma unroll
      for (int it = 0; it < 2; it++) {
        int rr = it * 8 + rb;
        uint4 vv = *(const uint4*)&tBuf[wave][rr][seg * 8];
        *(uint4*)(lgH + ((size_t)bh * 2304 + row0 + rr) * 2304 + wave * 576 +
                  g * 64 + seg * 8) = vv;
      }
      __syncthreads();
    }
  }
#pragma unroll
  for (int off = 1; off < 16; off <<= 1) {
#pragma unroll
    for (int i = 0; i < 4; i++) {
      s[i] += __shfl_xor(s[i], off);
      u[i] += __shfl_xor(u[i], off);
    }
  }
  if (m16 == 0) {
#pragma unroll
    for (int i = 0; i < 4; i++) {
      sWv[wave][quad * 4 + i] = s[i];
      uWv[wave][quad * 4 + i] = u[i];
    }
  }
  __syncthreads();
  if (tid < 16) {
    float S = sWv[0][tid] + sWv[1][tid] + sWv[2][tid] + sWv[3][tid];
    float U = uWv[0][tid] + uWv[1][tid] + uWv[2][tid] + uWv[3][tid];
    float er = __logf(S) - U / S;
    er += __shfl_xor(er, 1);
    er += __shfl_xor(er, 2);
    er += __shfl_xor(er, 4);
    er += __shfl_xor(er, 8);
    if (tid == 0) atomicAdd(&ent[bh], er);
  }
}

// K4: FUSED per-16-row-tile attention: QK^T MFMA -> LDS logit tile
// (row stride 2328 halves) -> per-row top-k (ballot bit-search, 2 rows
// per wave, no LDS ops) -> in-place masked exp -> PV MFMA (r4's 4-wave
// j-quarter split) -> oh. grid = 1152 (bh = blk&7 XCD affinity), 512
// thr. LDS ~74.6KB -> 2 blocks/CU; launch_bounds(512,4) -> 128 VGPR
// budget so search working set stays in arch VGPRs.
__global__ __launch_bounds__(512, 4) void k_attn_f(
    const _Float16* __restrict__ q2, const _Float16* __restrict__ k2,
    const _Float16* __restrict__ vt, const float* __restrict__ ent,
    const float* __restrict__ Wg1, const float* __restrict__ bg1,
    const float* __restrict__ Wg2, const float* __restrict__ bg2,
    float* __restrict__ oh) {
  __shared__ __align__(16) _Float16 lg[16 * LSTR];  // 74496 B
  __shared__ float sS[16];

  int blk = blockIdx.x;
  int bh = blk & 7;     // one bh per XCD -> q2/k2/vt slices L2-resident
  int tile = blk >> 3;  // 0..143
  int row0 = tile * 16;
  int tid = threadIdx.x, lane = tid & 63, wave = tid >> 6;
  int m16 = lane & 15, quad = lane >> 4;

  // ---- gate MLP (uniform) ----
  float eAvg = ent[bh] * (1.f / 2304.f);
  float gacc = bg2[0];
#pragma unroll
  for (int i = 0; i < 16; i++) {
    float h = fmaxf(fmaf(eAvg, Wg1[i], bg1[i]), 0.f);
    gacc = fmaf(h, Wg2[i], gacc);
  }
  float ratio = 0.9f / (1.f + __expf(-gacc)) + 0.1f;
  int kp = (int)ceilf(ratio * 2304.f);
  unsigned keep = (unsigned)min(max(kp, 1), 2304);

  // ---- phase 1: QK^T -> lg rows 0..15 ----
  {
    const half8_t* q2v =
        (const half8_t*)(q2 + ((size_t)bh * 2304 + row0 + m16) * 32);
    half8_t A1 = q2v[quad];
    half8_t zh = {};
    half8_t A2 = (lane < 32) ? A1 : zh;
    const half8_t* kbase = (const half8_t*)(k2 + (size_t)bh * 2304 * 32);
#pragma unroll 2
    for (int t = 0; t < 18; t++) {
      int col = wave * 288 + t * 16 + m16;
      const half8_t* kk = kbase + (size_t)col * 4;
      half8_t b1 = kk[quad & 1];
      half8_t b2 = kk[2 + (quad & 1)];
      floatx4 acc = {};
      acc = __builtin_amdgcn_mfma_f32_16x16x32_f16(A2, b2, acc, 0, 0, 0);
      acc = __builtin_amdgcn_mfma_f32_16x16x32_f16(A1, b1, acc, 0, 0, 0);
#pragma unroll
      for (int i = 0; i < 4; i++)
        lg[(quad * 4 + i) * LSTR + col] = (_Float16)acc[i];
    }
  }
  __syncthreads();

  // ---- phase 2: per-row top-k (ballot) + masked exp, 2 rows/wave ----
#pragma unroll 1
  for (int rr = 0; rr < 2; rr++) {
    int r = wave * 2 + rr;
    char* rb = (char*)lg + (size_t)r * (LSTR * 2);
    const uint4* s4 = (const uint4*)rb;
    uint4 q0 = s4[lane];
    uint4 q1 = s4[lane + 64];
    uint4 q2r = s4[lane + 128];
    uint4 q3 = s4[lane + 192];
    uint2 q4 = *(const uint2*)(rb + 4096 + lane * 8);
    unsigned wb[18] = {q0.x, q0.y, q0.z, q0.w, q1.x, q1.y, q1.z, q1.w,
                       q2r.x, q2r.y, q2r.z, q2r.w, q3.x, q3.y, q3.z, q3.w,
                       q4.x, q4.y};
    // ascending-key transform (packed), then unpack to 36 u32 regs
    unsigned ku[36];
#pragma unroll
    for (int i = 0; i < 18; i++) {
      unsigned kbi =
          wb[i] ^ (((wb[i] >> 15) & 0x00010001u) * 0x7FFFu + 0x80008000u);
      ku[2 * i + 0] = kbi & 0xFFFFu;
      ku[2 * i + 1] = kbi >> 16;
    }

    // exact k-th largest: 16-round ballot bit-search, no LDS traffic
    unsigned T = 0u;
    for (int bit = 15; bit >= 0; --bit) {
      unsigned cand = T | (1u << bit);
      unsigned cnt = 0u;
#pragma unroll
      for (int i = 0; i < 36; i++)
        cnt += (unsigned)__popcll(__ballot(ku[i] >= cand));
      if (cnt >= keep) {
        T = cand;  // uniform
        if (cnt == keep) break;
      }
    }
    _Float16 th_h = key_h(T);

    // masked exp, pack f16, write back in place (legacy sp pairing)
    float sp = 0.f;
    uint4* prow4 = (uint4*)rb;
#pragma unroll
    for (int g = 0; g < 4; g++) {
      uint4 o;
      unsigned ow[4];
#pragma unroll
      for (int wj = 0; wj < 4; wj++) {
        unsigned w = wb[g * 4 + wj];
        _Float16 hlo = ubits_h((unsigned short)(w & 0xFFFFu));
        _Float16 hhi = ubits_h((unsigned short)(w >> 16));
        float plo = (hlo >= th_h) ? __expf((float)hlo) : 0.f;
        float phi = (hhi >= th_h) ? __expf((float)hhi) : 0.f;
        __half2 hp = __floats2half2_rn(plo, phi);
        ow[wj] = *(unsigned*)&hp;
        if (wj == 0) sp += ((plo + phi));
      }
      // legacy pairing: ((p0+p1)+(p2+p3)) + ((p4+p5)+(p6+p7))
      o.x = ow[0]; o.y = ow[1]; o.z = ow[2]; o.w = ow[3];
      prow4[lane + g * 64] = o;
      {
        _Float16 h2a = ubits_h((unsigned short)(wb[g * 4 + 1] & 0xFFFFu));
        _Float16 h2b = ubits_h((unsigned short)(wb[g * 4 + 1] >> 16));
        _Float16 h3a = ubits_h((unsigned short)(wb[g * 4 + 2] & 0xFFFFu));
        _Float16 h3b = ubits_h((unsigned short)(wb[g * 4 + 2] >> 16));
        _Float16 h4a = ubits_h((unsigned short)(wb[g * 4 + 3] & 0xFFFFu));
        _Float16 h4b = ubits_h((unsigned short)(wb[g * 4 + 3] >> 16));
        float p2 = (h2a >= th_h) ? __expf((float)h2a) : 0.f;
        float p3 = (h2b >= th_h) ? __expf((float)h2b) : 0.f;
        float p4 = (h3a >= th_h) ? __expf((float)h3a) : 0.f;
        float p5 = (h3b >= th_h) ? __expf((float)h3b) : 0.f;
        float p6 = (h4a >= th_h) ? __expf((float)h4a) : 0.f;
        float p7 = (h4b >= th_h) ? __expf((float)h4b) : 0.f;
        sp += (p2 + p3);
        sp += (p4 + p5) + (p6 + p7);
      }
    }
    {
      _Float16 h0 = ubits_h((unsigned short)(wb[16] & 0xFFFFu));
      _Float16 h1 = ubits_h((unsigned short)(wb[16] >> 16));
      _Float16 h2 = ubits_h((unsigned short)(wb[17] & 0xFFFFu));
      _Float16 h3 = ubits_h((unsigned short)(wb[17] >> 16));
      float p0 = (h0 >= th_h) ? __expf((float)h0) : 0.f;
      float p1 = (h1 >= th_h) ? __expf((float)h1) : 0.f;
      float p2 = (h2 >= th_h) ? __expf((float)h2) : 0.f;
      float p3 = (h3 >= th_h) ? __expf((float)h3) : 0.f;
      sp += (p0 + p1) + (p2 + p3);
      uint2 o;
      __half2 hp0 = __floats2half2_rn(p0, p1); o.x = *(unsigned*)&hp0;
      __half2 hp1 = __floats2half2_rn(p2, p3); o.y = *(unsigned*)&hp1;
      *(uint2*)(rb + 4096 + lane * 8) = o;
    }
#pragma unroll
    for (int off = 1; off < 64; off <<= 1) sp += __shfl_xor(sp, off);
    if (lane == 0) sS[r] = sp;
  }
  __syncthreads();  // all rows' p visible; sS visible

  // ---- phase 3: PV via MFMA on waves 0-3 (r4's 4x576 j-split) ----
  floatx4 acc = {};
  if (wave < 4) {
    const _Float16* vrow = vt + ((size_t)bh * 16 + m16) * 2304;
    const _Float16* prow = lg + (size_t)m16 * LSTR;
    int jb0 = wave * 576 + quad * 8;
#pragma unroll 6
    for (int t = 0; t < 18; t++) {
      int jb = jb0 + t * 32;
      half8_t a2 = *(const half8_t*)&prow[jb];
      half8_t b2 = *(const half8_t*)&vrow[jb];
      acc = __builtin_amdgcn_mfma_f32_16x16x32_f16(a2, b2, acc, 0, 0, 0);
    }
  }
  __syncthreads();  // all lg reads done; safe to alias as reduction buf
  float* red = (float*)lg;
  if (wave < 4) {
#pragma unroll
    for (int i = 0; i < 4; i++)
      red[wave * 256 + (quad * 4 + i) * 16 + m16] = acc[i];
  }
  __syncthreads();
  if (tid < 256) {
    int r = tid >> 4;
    float s2 = red[0 * 256 + tid] + red[1 * 256 + tid] +
               red[2 * 256 + tid] + red[3 * 256 + tid];
    int d = tid & 15;
    oh[((size_t)(bh * 2304 + row0 + r)) * 16 + d] = s2 / sS[r];
  }
}

// K6: output projection, 4 output channels per block. grid = 2*16*9 = 288.
__global__ __launch_bounds__(256) void k_proj(const float* __restrict__ oh,
                                              const float* __restrict__ Wp,
                                              const float* __restrict__ bp,
                                              float* __restrict__ out) {
  int blk = blockIdx.x;
  int chunk = blk % 9;
  int cog = (blk / 9) % 16;
  int b = blk / (9 * 16);
  int co0 = cog * 4;
  int pos = chunk * 256 + threadIdx.x;
  float a0 = bp[co0 + 0], a1 = bp[co0 + 1], a2 = bp[co0 + 2], a3 = bp[co0 + 3];
#pragma unroll
  for (int head = 0; head < 4; head++) {
    const float4* op =
        (const float4*)(oh + ((size_t)((b * 4 + head) * 2304 + pos)) * 16);
#pragma unroll
    for (int p = 0; p < 4; p++) {
      float4 o4 = op[p];
#pragma unroll
      for (int i = 0; i < 4; i++) {
        const float* wr = Wp + (co0 + i) * 64 + head * 16 + p * 4;
        float* ai = (i == 0) ? &a0 : ((i == 1) ? &a1 : ((i == 2) ? &a2 : &a3));
        *ai = fmaf(wr[0], o4.x, *ai);
        *ai = fmaf(wr[1], o4.y, *ai);
        *ai = fmaf(wr[2], o4.z, *ai);
        *ai = fmaf(wr[3], o4.w, *ai);
      }
    }
  }
  out[(b * 64 + co0 + 0) * 2304 + pos] = a0;
  out[(b * 64 + co0 + 1) * 2304 + pos] = a1;
  out[(b * 64 + co0 + 2) * 2304 + pos] = a2;
  out[(b * 64 + co0 + 3) * 2304 + pos] = a3;
}

extern "C" void kernel_launch(void* const* d_in, const int* in_sizes, int n_in,
                              void* d_out, int out_size, void* d_ws,
                              size_t ws_size, hipStream_t stream) {
  const float* x    = (const float*)d_in[0];
  const float* Wqkv = (const float*)d_in[1];
  const float* bqkv = (const float*)d_in[2];
  const float* Wpos = (const float*)d_in[3];
  const float* bpos = (const float*)d_in[4];
  const float* Wg1  = (const float*)d_in[5];
  const float* bg1  = (const float*)d_in[6];
  const float* Wg2  = (const float*)d_in[7];
  const float* bg2  = (const float*)d_in[8];
  const float* Wpr  = (const float*)d_in[9];
  const float* bpr  = (const float*)d_in[10];
  float* out = (float*)d_out;

  // workspace (no logit cache)
  char* base = (char*)d_ws;
  float* qkv_raw = (float*)base;        // 884736 floats
  float* oh = qkv_raw + 884736;         // 294912 floats
  float* ent = oh + 294912;             // 8 floats
  _Float16* q2 = (_Float16*)(ent + 8);  // 589824 halves
  _Float16* k2 = q2 + 589824;           // 589824 halves
  _Float16* vt = k2 + 589824;           // 294912 halves (V^T f16 [bh][d][j])

  hipLaunchKernelGGL(k_qkv, dim3(2 * 48 * 9), dim3(256), 0, stream,
                     x, Wqkv, bqkv, qkv_raw, ent);
  hipLaunchKernelGGL(k_dw, dim3(432), dim3(256), 0, stream,
                     qkv_raw, Wpos, bpos, q2, k2, vt);
  hipLaunchKernelGGL((k_ent_t<false>), dim3(8 * 144), dim3(256), 0, stream,
                     q2, k2, ent, (_Float16*)nullptr);
  hipLaunchKernelGGL(k_attn_f, dim3(1152), dim3(512), 0, stream,
                     q2, k2, vt, ent, Wg1, bg1, Wg2, bg2, oh);
  hipLaunchKernelGGL(k_proj, dim3(2 * 16 * 9), dim3(256), 0, stream,
                     oh, Wpr, bpr, out);
}

// Round 8
// 196.606 us; speedup vs baseline: 1.1668x; 1.0607x over previous
//
#include <hip/hip_runtime.h>
#include <hip/hip_fp16.h>

// b=2, c=64, 48x48 -> n=2304, heads=4, hd=16. n = 9*256 = 144*16.
// r25: fused cache-free attention, 16-row tiles, 1024-THREAD blocks.
// Evidence chain: r4-r7 showed the fused kernel is LATENCY-bound (all
// counters low: VALU 36%, MFMA 3%, HBM 0.4%, conflicts ~0; hist-vs-
// ballot, conflicts 8.6M-vs-0.4M, VGPR 32-vs-52 all changed NOTHING;
// only tile size mattered). 4 waves/SIMD can't hide the 16-round serial
// ballot chain x 2 rows/wave. r25: 16 waves/block -> 1 row/wave (chain
// halves) and 2 blocks/CU -> 8 waves/SIMD (hiding doubles); LDS 74.5KB
// x2 = 149KB fits 160KB/CU. launch_bounds(1024,8) caps VGPR at 64 (r7
// compiled to 52 -- fits). Phase 1: 9 col-tiles/wave. Phase 3 verbatim
// r7 (waves 0-3, bit-exact legacy PV+reduce). Output bit-path fully
// preserved. SEPARATE k_proj (r17: fused atomic projection 60->94us -
// do not revisit). k_dw: 432 blocks (r17-kept).

typedef _Float16 half8_t __attribute__((ext_vector_type(8)));
typedef float floatx4 __attribute__((ext_vector_type(4)));

#define LSTR 2328  // lg row stride in halves (4656B; 1164 dw = 12 mod 32)

union HU { unsigned short s; _Float16 h; };
__device__ __forceinline__ _Float16 ubits_h(unsigned short u) {
  HU c; c.s = u; return c.h;
}
// ascending 16-bit key -> the f16 value it encodes
__device__ __forceinline__ _Float16 key_h(unsigned k) {
  unsigned short u = (k & 0x8000u) ? (unsigned short)(k & 0x7FFFu)
                                   : (unsigned short)((~k) & 0xFFFFu);
  return ubits_h(u);
}

// K1: 1x1 conv, 4 output channels per block. grid = 2*48*9 = 864;
// also zeroes ent[] (replaces memset dispatch).
__global__ __launch_bounds__(256) void k_qkv(const float* __restrict__ x,
                                             const float* __restrict__ W,
                                             const float* __restrict__ bias,
                                             float* __restrict__ out,
                                             float* __restrict__ ent) {
  if (blockIdx.x == 0 && threadIdx.x < 8) ent[threadIdx.x] = 0.f;
  int blk = blockIdx.x;
  int chunk = blk % 9;
  int og = (blk / 9) % 48;
  int b = blk / (9 * 48);
  int o0 = og * 4;
  int pos = chunk * 256 + threadIdx.x;
  const float* xb = x + b * 64 * 2304 + pos;
  const float* w0 = W + (o0 + 0) * 64;
  const float* w1 = W + (o0 + 1) * 64;
  const float* w2 = W + (o0 + 2) * 64;
  const float* w3 = W + (o0 + 3) * 64;
  float a0 = bias[o0 + 0], a1 = bias[o0 + 1];
  float a2 = bias[o0 + 2], a3 = bias[o0 + 3];
#pragma unroll
  for (int c = 0; c < 64; c++) {
    float xv = xb[c * 2304];
    a0 = fmaf(w0[c], xv, a0);
    a1 = fmaf(w1[c], xv, a1);
    a2 = fmaf(w2[c], xv, a2);
    a3 = fmaf(w3[c], xv, a3);
  }
  out[(b * 192 + o0 + 0) * 2304 + pos] = a0;
  out[(b * 192 + o0 + 1) * 2304 + pos] = a1;
  out[(b * 192 + o0 + 2) * 2304 + pos] = a2;
  out[(b * 192 + o0 + 3) * 2304 + pos] = a3;
}

// K2: 3x3 depthwise conv, 8 channels per block with LDS staging; q/k
// packed per-row-half stores (2x 16B contiguous). grid = 432.
__global__ __launch_bounds__(256) void k_dw(const float* __restrict__ qkv,
                                            const float* __restrict__ Wpos,
                                            const float* __restrict__ bpos,
                                            _Float16* __restrict__ q2,
                                            _Float16* __restrict__ k2,
                                            _Float16* __restrict__ vt) {
  __shared__ float smem[8][384];  // 8 ch x 8 rows x 48 = 12.3 KB
  int blk = blockIdx.x;
  int chunk = blk % 9;
  int half = (blk / 9) % 2;
  int sel = (blk / 18) % 3;
  int head = (blk / 54) % 4;
  int b = blk / 216;
  int chbase = sel * 64 + head * 16 + half * 8;
  int bh = b * 4 + head;
  int tid = threadIdx.x;
  int p0 = chunk * 256;
  int baserow = p0 / 48;
  int rA = min(max(baserow - 1, 0), 40);  // 8-row window within [0,47]

  const float* src = qkv + (size_t)(b * 192 + chbase) * 2304;
#pragma unroll
  for (int l = 0; l < 12; l++) {
    int idx = tid + l * 256;
    int ch = idx / 384;
    int off = idx - ch * 384;
    int rr = off / 48;
    int cc = off - rr * 48;
    smem[ch][off] = src[(size_t)ch * 2304 + (rA + rr) * 48 + cc];
  }
  __syncthreads();

  int pos = p0 + tid;
  int yy = pos / 48, xx = pos - yy * 48;
  int ry = yy - rA;
  float accv[8];
#pragma unroll
  for (int d = 0; d < 8; d++) {
    const float* w = Wpos + (chbase + d) * 9;
    float a = bpos[chbase + d];
#pragma unroll
    for (int dy = -1; dy <= 1; dy++) {
      int y2 = yy + dy;
      if ((unsigned)y2 < 48u) {
#pragma unroll
        for (int dx = -1; dx <= 1; dx++) {
          int x2 = xx + dx;
          if ((unsigned)x2 < 48u)
            a = fmaf(w[(dy + 1) * 3 + (dx + 1)], smem[d][(ry + dy) * 48 + x2],
                     a);
        }
      }
    }
    accv[d] = a;
  }

  if (sel == 2) {
#pragma unroll
    for (int d = 0; d < 8; d++)
      vt[((size_t)bh * 16 + half * 8 + d) * 2304 + pos] = (_Float16)accv[d];
  } else {
    _Float16 h1[8], h2[8];
#pragma unroll
    for (int d = 0; d < 8; d++) {
      float a = (sel == 0) ? accv[d] * 0.25f : accv[d];
      h1[d] = (_Float16)a;
      h2[d] = (_Float16)(a - (float)h1[d]);
    }
    _Float16* dst = ((sel == 0) ? q2 : k2) + ((size_t)bh * 2304 + pos) * 32;
    *(uint4*)(dst + half * 8) = *(uint4*)&h1[0];
    *(uint4*)(dst + 16 + half * 8) = *(uint4*)&h2[0];
  }
}

// K3: SINGLE-PASS MFMA QK^T: entropy sums (shift-invariant, no max).
// STORE=false: no logit store, no barriers. grid = 8*144, 256 thr.
template <bool STORE>
__global__ __launch_bounds__(256) void k_ent_t(const _Float16* __restrict__ q2,
                                               const _Float16* __restrict__ k2,
                                               float* __restrict__ ent,
                                               _Float16* __restrict__ lgH) {
  __shared__ __align__(16) _Float16 tBuf[4][16][72];
  __shared__ float sWv[4][16], uWv[4][16];

  int blk = blockIdx.x;
  int rowtile = blk % 144;
  int bh = blk / 144;
  int row0 = rowtile * 16;
  int tid = threadIdx.x, lane = tid & 63, wave = tid >> 6;
  int m16 = lane & 15, quad = lane >> 4;

  const half8_t* q2v =
      (const half8_t*)(q2 + ((size_t)bh * 2304 + row0 + m16) * 32);
  half8_t A1 = q2v[quad];
  half8_t zh = {};
  half8_t A2 = (lane < 32) ? A1 : zh;
  const half8_t* kbase = (const half8_t*)(k2 + (size_t)bh * 2304 * 32);

  // s0 = sum e^a, u0 = sum a e^a  (entropy = log s0 - u0/s0; shift-inv.)
  float s[4] = {0.f, 0.f, 0.f, 0.f}, u[4] = {0.f, 0.f, 0.f, 0.f};
  for (int g = 0; g < 9; g++) {
#pragma unroll
    for (int tt = 0; tt < 4; tt++) {
      int t = g * 4 + tt;
      int col = wave * 576 + t * 16 + m16;
      const half8_t* kk = kbase + (size_t)col * 4;
      half8_t b1 = kk[quad & 1];
      half8_t b2 = kk[2 + (quad & 1)];
      floatx4 acc = {};
      acc = __builtin_amdgcn_mfma_f32_16x16x32_f16(A2, b2, acc, 0, 0, 0);
      acc = __builtin_amdgcn_mfma_f32_16x16x32_f16(A1, b1, acc, 0, 0, 0);
#pragma unroll
      for (int i = 0; i < 4; i++) {
        if (STORE) tBuf[wave][quad * 4 + i][tt * 16 + m16] = (_Float16)acc[i];
        float e = __expf(acc[i]);
        s[i] += e;
        u[i] = fmaf(acc[i], e, u[i]);
      }
    }
    if (STORE) {
      __syncthreads();
      int rb = lane >> 3, seg = lane & 7;
#pragma unroll
      for (int it = 0; it < 2; it++) {
        int rr = it * 8 + rb;
        uint4 vv = *(const uint4*)&tBuf[wave][rr][seg * 8];
        *(uint4*)(lgH + ((size_t)bh * 2304 + row0 + rr) * 2304 + wave * 576 +
                  g * 64 + seg * 8) = vv;
      }
      __syncthreads();
    }
  }
#pragma unroll
  for (int off = 1; off < 16; off <<= 1) {
#pragma unroll
    for (int i = 0; i < 4; i++) {
      s[i] += __shfl_xor(s[i], off);
      u[i] += __shfl_xor(u[i], off);
    }
  }
  if (m16 == 0) {
#pragma unroll
    for (int i = 0; i < 4; i++) {
      sWv[wave][quad * 4 + i] = s[i];
      uWv[wave][quad * 4 + i] = u[i];
    }
  }
  __syncthreads();
  if (tid < 16) {
    float S = sWv[0][tid] + sWv[1][tid] + sWv[2][tid] + sWv[3][tid];
    float U = uWv[0][tid] + uWv[1][tid] + uWv[2][tid] + uWv[3][tid];
    float er = __logf(S) - U / S;
    er += __shfl_xor(er, 1);
    er += __shfl_xor(er, 2);
    er += __shfl_xor(er, 4);
    er += __shfl_xor(er, 8);
    if (tid == 0) atomicAdd(&ent[bh], er);
  }
}

// K4: FUSED per-16-row-tile attention, 1024 thr (16 waves): QK^T MFMA
// (9 col-tiles/wave) -> LDS logit tile (row stride 2328 halves) ->
// per-row top-k (ballot bit-search, 1 ROW PER WAVE, no LDS ops) ->
// in-place masked exp -> PV MFMA (waves 0-3, legacy 4x576 j-split) ->
// oh. grid = 1152 (bh = blk&7 XCD affinity). LDS 74.5KB, 2 blocks/CU
// -> 32 waves/CU (8/SIMD). launch_bounds(1024,8) caps VGPR at 64.
__global__ __launch_bounds__(1024, 8) void k_attn_f(
    const _Float16* __restrict__ q2, const _Float16* __restrict__ k2,
    const _Float16* __restrict__ vt, const float* __restrict__ ent,
    const float* __restrict__ Wg1, const float* __restrict__ bg1,
    const float* __restrict__ Wg2, const float* __restrict__ bg2,
    float* __restrict__ oh) {
  __shared__ __align__(16) _Float16 lg[16 * LSTR];  // 74496 B
  __shared__ float sS[16];

  int blk = blockIdx.x;
  int bh = blk & 7;     // one bh per XCD -> q2/k2/vt slices L2-resident
  int tile = blk >> 3;  // 0..143
  int row0 = tile * 16;
  int tid = threadIdx.x, lane = tid & 63, wave = tid >> 6;
  int m16 = lane & 15, quad = lane >> 4;

  // ---- gate MLP (uniform) ----
  float eAvg = ent[bh] * (1.f / 2304.f);
  float gacc = bg2[0];
#pragma unroll
  for (int i = 0; i < 16; i++) {
    float h = fmaxf(fmaf(eAvg, Wg1[i], bg1[i]), 0.f);
    gacc = fmaf(h, Wg2[i], gacc);
  }
  float ratio = 0.9f / (1.f + __expf(-gacc)) + 0.1f;
  int kp = (int)ceilf(ratio * 2304.f);
  unsigned keep = (unsigned)min(max(kp, 1), 2304);

  // ---- phase 1: QK^T -> lg rows 0..15 (9 col-tiles per wave) ----
  {
    const half8_t* q2v =
        (const half8_t*)(q2 + ((size_t)bh * 2304 + row0 + m16) * 32);
    half8_t A1 = q2v[quad];
    half8_t zh = {};
    half8_t A2 = (lane < 32) ? A1 : zh;
    const half8_t* kbase = (const half8_t*)(k2 + (size_t)bh * 2304 * 32);
#pragma unroll 3
    for (int t = 0; t < 9; t++) {
      int col = wave * 144 + t * 16 + m16;
      const half8_t* kk = kbase + (size_t)col * 4;
      half8_t b1 = kk[quad & 1];
      half8_t b2 = kk[2 + (quad & 1)];
      floatx4 acc = {};
      acc = __builtin_amdgcn_mfma_f32_16x16x32_f16(A2, b2, acc, 0, 0, 0);
      acc = __builtin_amdgcn_mfma_f32_16x16x32_f16(A1, b1, acc, 0, 0, 0);
#pragma unroll
      for (int i = 0; i < 4; i++)
        lg[(quad * 4 + i) * LSTR + col] = (_Float16)acc[i];
    }
  }
  __syncthreads();

  // ---- phase 2: per-row top-k (ballot) + masked exp, 1 row/wave ----
  {
    int r = wave;
    char* rb = (char*)lg + (size_t)r * (LSTR * 2);
    const uint4* s4 = (const uint4*)rb;
    uint4 q0 = s4[lane];
    uint4 q1 = s4[lane + 64];
    uint4 q2r = s4[lane + 128];
    uint4 q3 = s4[lane + 192];
    uint2 q4 = *(const uint2*)(rb + 4096 + lane * 8);
    unsigned wb[18] = {q0.x, q0.y, q0.z, q0.w, q1.x, q1.y, q1.z, q1.w,
                       q2r.x, q2r.y, q2r.z, q2r.w, q3.x, q3.y, q3.z, q3.w,
                       q4.x, q4.y};
    // ascending-key transform (packed), then unpack to 36 u32 regs
    unsigned ku[36];
#pragma unroll
    for (int i = 0; i < 18; i++) {
      unsigned kbi =
          wb[i] ^ (((wb[i] >> 15) & 0x00010001u) * 0x7FFFu + 0x80008000u);
      ku[2 * i + 0] = kbi & 0xFFFFu;
      ku[2 * i + 1] = kbi >> 16;
    }

    // exact k-th largest: 16-round ballot bit-search, no LDS traffic
    unsigned T = 0u;
    for (int bit = 15; bit >= 0; --bit) {
      unsigned cand = T | (1u << bit);
      unsigned cnt = 0u;
#pragma unroll
      for (int i = 0; i < 36; i++)
        cnt += (unsigned)__popcll(__ballot(ku[i] >= cand));
      if (cnt >= keep) {
        T = cand;  // uniform
        if (cnt == keep) break;
      }
    }
    _Float16 th_h = key_h(T);

    // masked exp, pack f16, write back in place (legacy sp pairing)
    float sp = 0.f;
    uint4* prow4 = (uint4*)rb;
#pragma unroll
    for (int g = 0; g < 4; g++) {
      uint4 o;
      unsigned ow[4];
#pragma unroll
      for (int wj = 0; wj < 4; wj++) {
        unsigned w = wb[g * 4 + wj];
        _Float16 hlo = ubits_h((unsigned short)(w & 0xFFFFu));
        _Float16 hhi = ubits_h((unsigned short)(w >> 16));
        float plo = (hlo >= th_h) ? __expf((float)hlo) : 0.f;
        float phi = (hhi >= th_h) ? __expf((float)hhi) : 0.f;
        __half2 hp = __floats2half2_rn(plo, phi);
        ow[wj] = *(unsigned*)&hp;
        if (wj == 0) sp += ((plo + phi));
      }
      // legacy pairing: ((p0+p1)+(p2+p3)) + ((p4+p5)+(p6+p7))
      o.x = ow[0]; o.y = ow[1]; o.z = ow[2]; o.w = ow[3];
      prow4[lane + g * 64] = o;
      {
        _Float16 h2a = ubits_h((unsigned short)(wb[g * 4 + 1] & 0xFFFFu));
        _Float16 h2b = ubits_h((unsigned short)(wb[g * 4 + 1] >> 16));
        _Float16 h3a = ubits_h((unsigned short)(wb[g * 4 + 2] & 0xFFFFu));
        _Float16 h3b = ubits_h((unsigned short)(wb[g * 4 + 2] >> 16));
        _Float16 h4a = ubits_h((unsigned short)(wb[g * 4 + 3] & 0xFFFFu));
        _Float16 h4b = ubits_h((unsigned short)(wb[g * 4 + 3] >> 16));
        float p2 = (h2a >= th_h) ? __expf((float)h2a) : 0.f;
        float p3 = (h2b >= th_h) ? __expf((float)h2b) : 0.f;
        float p4 = (h3a >= th_h) ? __expf((float)h3a) : 0.f;
        float p5 = (h3b >= th_h) ? __expf((float)h3b) : 0.f;
        float p6 = (h4a >= th_h) ? __expf((float)h4a) : 0.f;
        float p7 = (h4b >= th_h) ? __expf((float)h4b) : 0.f;
        sp += (p2 + p3);
        sp += (p4 + p5) + (p6 + p7);
      }
    }
    {
      _Float16 h0 = ubits_h((unsigned short)(wb[16] & 0xFFFFu));
      _Float16 h1 = ubits_h((unsigned short)(wb[16] >> 16));
      _Float16 h2 = ubits_h((unsigned short)(wb[17] & 0xFFFFu));
      _Float16 h3 = ubits_h((unsigned short)(wb[17] >> 16));
      float p0 = (h0 >= th_h) ? __expf((float)h0) : 0.f;
      float p1 = (h1 >= th_h) ? __expf((float)h1) : 0.f;
      float p2 = (h2 >= th_h) ? __expf((float)h2) : 0.f;
      float p3 = (h3 >= th_h) ? __expf((float)h3) : 0.f;
      sp += (p0 + p1) + (p2 + p3);
      uint2 o;
      __half2 hp0 = __floats2half2_rn(p0, p1); o.x = *(unsigned*)&hp0;
      __half2 hp1 = __floats2half2_rn(p2, p3); o.y = *(unsigned*)&hp1;
      *(uint2*)(rb + 4096 + lane * 8) = o;
    }
#pragma unroll
    for (int off = 1; off < 64; off <<= 1) sp += __shfl_xor(sp, off);
    if (lane == 0) sS[r] = sp;
  }
  __syncthreads();  // all rows' p visible; sS visible

  // ---- phase 3: PV via MFMA on waves 0-3 (legacy 4x576 j-split) ----
  floatx4 acc = {};
  if (wave < 4) {
    const _Float16* vrow = vt + ((size_t)bh * 16 + m16) * 2304;
    const _Float16* prow = lg + (size_t)m16 * LSTR;
    int jb0 = wave * 576 + quad * 8;
#pragma unroll 6
    for (int t = 0; t < 18; t++) {
      int jb = jb0 + t * 32;
      half8_t a2 = *(const half8_t*)&prow[jb];
      half8_t b2 = *(const half8_t*)&vrow[jb];
      acc = __builtin_amdgcn_mfma_f32_16x16x32_f16(a2, b2, acc, 0, 0, 0);
    }
  }
  __syncthreads();  // all lg reads done; safe to alias as reduction buf
  float* red = (float*)lg;
  if (wave < 4) {
#pragma unroll
    for (int i = 0; i < 4; i++)
      red[wave * 256 + (quad * 4 + i) * 16 + m16] = acc[i];
  }
  __syncthreads();
  if (tid < 256) {
    int r = tid >> 4;
    float s2 = red[0 * 256 + tid] + red[1 * 256 + tid] +
               red[2 * 256 + tid] + red[3 * 256 + tid];
    int d = tid & 15;
    oh[((size_t)(bh * 2304 + row0 + r)) * 16 + d] = s2 / sS[r];
  }
}

// K6: output projection, 4 output channels per block. grid = 2*16*9 = 288.
__global__ __launch_bounds__(256) void k_proj(const float* __restrict__ oh,
                                              const float* __restrict__ Wp,
                                              const float* __restrict__ bp,
                                              float* __restrict__ out) {
  int blk = blockIdx.x;
  int chunk = blk % 9;
  int cog = (blk / 9) % 16;
  int b = blk / (9 * 16);
  int co0 = cog * 4;
  int pos = chunk * 256 + threadIdx.x;
  float a0 = bp[co0 + 0], a1 = bp[co0 + 1], a2 = bp[co0 + 2], a3 = bp[co0 + 3];
#pragma unroll
  for (int head = 0; head < 4; head++) {
    const float4* op =
        (const float4*)(oh + ((size_t)((b * 4 + head) * 2304 + pos)) * 16);
#pragma unroll
    for (int p = 0; p < 4; p++) {
      float4 o4 = op[p];
#pragma unroll
      for (int i = 0; i < 4; i++) {
        const float* wr = Wp + (co0 + i) * 64 + head * 16 + p * 4;
        float* ai = (i == 0) ? &a0 : ((i == 1) ? &a1 : ((i == 2) ? &a2 : &a3));
        *ai = fmaf(wr[0], o4.x, *ai);
        *ai = fmaf(wr[1], o4.y, *ai);
        *ai = fmaf(wr[2], o4.z, *ai);
        *ai = fmaf(wr[3], o4.w, *ai);
      }
    }
  }
  out[(b * 64 + co0 + 0) * 2304 + pos] = a0;
  out[(b * 64 + co0 + 1) * 2304 + pos] = a1;
  out[(b * 64 + co0 + 2) * 2304 + pos] = a2;
  out[(b * 64 + co0 + 3) * 2304 + pos] = a3;
}

extern "C" void kernel_launch(void* const* d_in, const int* in_sizes, int n_in,
                              void* d_out, int out_size, void* d_ws,
                              size_t ws_size, hipStream_t stream) {
  const float* x    = (const float*)d_in[0];
  const float* Wqkv = (const float*)d_in[1];
  const float* bqkv = (const float*)d_in[2];
  const float* Wpos = (const float*)d_in[3];
  const float* bpos = (const float*)d_in[4];
  const float* Wg1  = (const float*)d_in[5];
  const float* bg1  = (const float*)d_in[6];
  const float* Wg2  = (const float*)d_in[7];
  const float* bg2  = (const float*)d_in[8];
  const float* Wpr  = (const float*)d_in[9];
  const float* bpr  = (const float*)d_in[10];
  float* out = (float*)d_out;

  // workspace (no logit cache)
  char* base = (char*)d_ws;
  float* qkv_raw = (float*)base;        // 884736 floats
  float* oh = qkv_raw + 884736;         // 294912 floats
  float* ent = oh + 294912;             // 8 floats
  _Float16* q2 = (_Float16*)(ent + 8);  // 589824 halves
  _Float16* k2 = q2 + 589824;           // 589824 halves
  _Float16* vt = k2 + 589824;           // 294912 halves (V^T f16 [bh][d][j])

  hipLaunchKernelGGL(k_qkv, dim3(2 * 48 * 9), dim3(256), 0, stream,
                     x, Wqkv, bqkv, qkv_raw, ent);
  hipLaunchKernelGGL(k_dw, dim3(432), dim3(256), 0, stream,
                     qkv_raw, Wpos, bpos, q2, k2, vt);
  hipLaunchKernelGGL((k_ent_t<false>), dim3(8 * 144), dim3(256), 0, stream,
                     q2, k2, ent, (_Float16*)nullptr);
  hipLaunchKernelGGL(k_attn_f, dim3(1152), dim3(1024), 0, stream,
                     q2, k2, vt, ent, Wg1, bg1, Wg2, bg2, oh);
  hipLaunchKernelGGL(k_proj, dim3(2 * 16 * 9), dim3(256), 0, stream,
                     oh, Wpr, bpr, out);
}